// Round 8
// baseline (636.502 us; speedup 1.0000x reference)
//
#include <hip/hip_runtime.h>
#include <cstdint>

#define CKDIM 128
#define MDIM  4096
#define QDIM  4096
#define BATCH 4

typedef __attribute__((ext_vector_type(8))) _Float16 half8;
typedef __attribute__((ext_vector_type(4))) float    f32x4;

#if __has_builtin(__builtin_amdgcn_exp2f)
#define EXP2(x) __builtin_amdgcn_exp2f(x)
#else
#define EXP2(x) exp2f(x)
#endif

#define ALPHA 0.12753139626596757f    // log2(e)/sqrt(128)
#define K2A   0.25506279253193514f    // 2*ALPHA

__device__ inline void gl_lds16(const void* g, void* l) {
    __builtin_amdgcn_global_load_lds(
        (const __attribute__((address_space(1))) unsigned*)g,
        (__attribute__((address_space(3))) unsigned*)l, 16, 0, 0);
}

// ---- 1) fused: transpose-convert X[b][k][n] fp32 -> Xt[b][n][k] fp16,
//      cm[b][m] = -ALPHA*sum_k Mk^2 (fp32-exact), sums[] zeroing by Qk half.
__global__ void convert_kernel(const float* __restrict__ Mk, const float* __restrict__ Qk,
                               _Float16* __restrict__ At, _Float16* __restrict__ Bt,
                               float* __restrict__ cm, float* __restrict__ sums) {
    __shared__ _Float16 T[128 * 130];
    __shared__ float    asqp[16][128];
    const int blk = blockIdx.x;                  // 256: mat(2) x b(4) x tile(32)
    const int mat = blk >> 7;
    const int b   = (blk >> 5) & 3;
    const int t   = blk & 31;
    const float*  src = (mat ? Qk : Mk) + (size_t)b * CKDIM * MDIM + t * 128;
    _Float16*     dst = (mat ? Bt : At) + ((size_t)b * MDIM + (size_t)t * 128) * CKDIM;
    const int tid = threadIdx.x;
    const int kg  = tid >> 4;
    const int ng  = tid & 15;

    float sq[8] = {0.f, 0.f, 0.f, 0.f, 0.f, 0.f, 0.f, 0.f};
    #pragma unroll
    for (int it = 0; it < 8; ++it) {
        int k = it * 16 + kg;
        const float* g = src + (size_t)k * MDIM + ng * 8;
        float4 v0 = *(const float4*)g;
        float4 v1 = *(const float4*)(g + 4);
        _Float16* p = &T[k * 130 + ng * 8];
        p[0] = (_Float16)v0.x; p[1] = (_Float16)v0.y; p[2] = (_Float16)v0.z; p[3] = (_Float16)v0.w;
        p[4] = (_Float16)v1.x; p[5] = (_Float16)v1.y; p[6] = (_Float16)v1.z; p[7] = (_Float16)v1.w;
        if (mat == 0) {
            sq[0] += v0.x * v0.x; sq[1] += v0.y * v0.y;
            sq[2] += v0.z * v0.z; sq[3] += v0.w * v0.w;
            sq[4] += v1.x * v1.x; sq[5] += v1.y * v1.y;
            sq[6] += v1.z * v1.z; sq[7] += v1.w * v1.w;
        }
    }
    if (mat == 0) {
        #pragma unroll
        for (int j = 0; j < 8; ++j) asqp[kg][ng * 8 + j] = sq[j];
    } else {
        if (tid < 128) sums[(blk & 127) * 128 + tid] = 0.f;
    }
    __syncthreads();
    #pragma unroll
    for (int it = 0; it < 8; ++it) {
        int pid = it * 256 + tid;
        int n = pid >> 4, c = pid & 15;
        half8 o;
        #pragma unroll
        for (int j = 0; j < 8; ++j) o[j] = T[(c * 8 + j) * 130 + n];
        *(half8*)(dst + (size_t)n * CKDIM + c * 8) = o;
    }
    if (mat == 0 && tid < 128) {
        float s = 0.f;
        #pragma unroll
        for (int g = 0; g < 16; ++g) s += asqp[g][tid];
        cm[b * MDIM + t * 128 + tid] = -ALPHA * s;
    }
}

// ---- 2/3) q-stripe GEMM passes — INSTRUMENTED (round 8 diagnostic).
// Identical inner structure to round 7, but the A-stream phase repeats
// REPS times inside one dispatch so the dispatch duration exceeds the
// harness fill kernels (~170 us) and surfaces in rocprof's top-5 WITH
// counters. p0 = dur/16, p1 = dur/4. Output values are unchanged:
// pass0 scales colsum by exactly 1/16; pass1 re-writes identical bytes.
template <int WRITE>
__global__ __launch_bounds__(512, 2) void gemm_pass(
        const _Float16* __restrict__ At, const _Float16* __restrict__ Bt,
        const float* __restrict__ cmArr, float* __restrict__ sums,
        float* __restrict__ out) {
    __shared__ __align__(16) char ldsB[65536];       // [256 q][128 k] fp16 swz
    __shared__ __align__(16) char ldsA[2][16384];    // [64 m][128 k] fp16 swz
    __shared__ float red[2][256];

    const int tid  = threadIdx.x;
    const int lane = tid & 63;
    const int wv   = tid >> 6;       // 0..7
    const int wr   = wv >> 2;        // 0..1  (32 m-rows each)
    const int wq   = wv & 3;         // 0..3  (64 q-cols each)
    const int g4   = lane >> 4;
    const int i    = lane & 15;

    const int wg = blockIdx.x;       // 256
    const int c  = wg & 15;
    const int qs = wg >> 4;
    const int b  = c >> 2;
    const int q0 = qs << 8;
    const int m0 = (c & 3) << 10;

    const char* Ab = (const char*)(At + ((size_t)b * MDIM + m0) * CKDIM);
    const char* Bb = (const char*)(Bt + ((size_t)b * QDIM + q0) * CKDIM);

    // ---- prologue: stage B stripe (64 KB) once
    #pragma unroll
    for (int r = 0; r < 8; ++r) {
        int ch = r * 8 + wv;
        unsigned D = ((unsigned)ch << 10) + (unsigned)lane * 16;
        unsigned S = D ^ (((D >> 8) & 7u) << 4);
        gl_lds16(Bb + S, ldsB + ((unsigned)ch << 10));
    }
    float rs[4];
    if (WRITE) {
        #pragma unroll
        for (int nf = 0; nf < 4; ++nf)
            rs[nf] = 1.0f / sums[(b << 12) + q0 + wq * 64 + nf * 16 + i];
    }
    asm volatile("s_waitcnt vmcnt(0)" ::: "memory");
    __syncthreads();

    float colsum[4] = {0.f, 0.f, 0.f, 0.f};
    constexpr int REPS = WRITE ? 4 : 16;

    #pragma unroll 1
    for (int rep = 0; rep < REPS; ++rep) {
        // (re-)stage A tile 0
        #pragma unroll
        for (int r = 0; r < 2; ++r) {
            int ch = wv * 2 + r;
            unsigned D = ((unsigned)ch << 10) + (unsigned)lane * 16;
            unsigned S = D ^ (((D >> 8) & 7u) << 4);
            gl_lds16(Ab + S, ldsA[0] + ((unsigned)ch << 10));
        }
        asm volatile("s_waitcnt vmcnt(0)" ::: "memory");
        __syncthreads();

        #pragma unroll 1
        for (int mt = 0; mt < 16; ++mt) {
            const char* lA = ldsA[mt & 1];
            if (mt + 1 < 16) {
                char* dst = ldsA[(mt + 1) & 1];
                #pragma unroll
                for (int r = 0; r < 2; ++r) {
                    int ch = wv * 2 + r;
                    unsigned D = ((unsigned)ch << 10) + (unsigned)lane * 16;
                    unsigned S = D ^ (((D >> 8) & 7u) << 4);
                    gl_lds16(Ab + ((unsigned)(mt + 1) << 14) + S, dst + ((unsigned)ch << 10));
                }
            }
            __builtin_amdgcn_sched_barrier(0);

            f32x4 cmv0 = *(const f32x4*)&cmArr[(b << 12) + m0 + mt * 64 + wr * 32 + g4 * 4];
            f32x4 cmv1 = *(const f32x4*)&cmArr[(b << 12) + m0 + mt * 64 + wr * 32 + 16 + g4 * 4];

            f32x4 acc[2][4] = {};
            #pragma unroll
            for (int t = 0; t < 4; ++t) {
                const int kb = t * 64 + g4 * 16;
                half8 a0, a1, bf[4];
                { int n = wr * 32 + i;      a0 = *(const half8*)(lA + n * 256 + (kb ^ ((n & 7) << 4))); }
                { int n = wr * 32 + 16 + i; a1 = *(const half8*)(lA + n * 256 + (kb ^ ((n & 7) << 4))); }
                #pragma unroll
                for (int nf = 0; nf < 4; ++nf) {
                    int n = wq * 64 + nf * 16 + i;
                    bf[nf] = *(const half8*)(ldsB + n * 256 + (kb ^ ((n & 7) << 4)));
                }
                #pragma unroll
                for (int nf = 0; nf < 4; ++nf) {
                    acc[0][nf] = __builtin_amdgcn_mfma_f32_16x16x32_f16(a0, bf[nf], acc[0][nf], 0, 0, 0);
                    acc[1][nf] = __builtin_amdgcn_mfma_f32_16x16x32_f16(a1, bf[nf], acc[1][nf], 0, 0, 0);
                }
            }

            if (WRITE) {
                #pragma unroll
                for (int mf = 0; mf < 2; ++mf) {
                    f32x4  cmv  = mf ? cmv1 : cmv0;
                    size_t mrow = (size_t)(m0 + mt * 64 + wr * 32 + mf * 16 + g4 * 4);
                    size_t base = ((((size_t)b << 12) + mrow) << 12) + (q0 + wq * 64 + i);
                    #pragma unroll
                    for (int nf = 0; nf < 4; ++nf)
                        #pragma unroll
                        for (int r = 0; r < 4; ++r) {
                            float e = EXP2(fmaf(acc[mf][nf][r], K2A, cmv[r])) * rs[nf];
                            __builtin_nontemporal_store(e, &out[base + ((size_t)r << 12) + nf * 16]);
                        }
                }
            } else {
                #pragma unroll
                for (int mf = 0; mf < 2; ++mf) {
                    f32x4 cmv = mf ? cmv1 : cmv0;
                    #pragma unroll
                    for (int nf = 0; nf < 4; ++nf)
                        #pragma unroll
                        for (int r = 0; r < 4; ++r)
                            colsum[nf] += EXP2(fmaf(acc[mf][nf][r], K2A, cmv[r]));
                }
            }

            if (mt + 1 < 16) {
                if (WRITE) asm volatile("s_waitcnt vmcnt(32)" ::: "memory");
                else       asm volatile("s_waitcnt vmcnt(2)"  ::: "memory");
                __builtin_amdgcn_s_barrier();
                __builtin_amdgcn_sched_barrier(0);
            }
        }
        __syncthreads();   // rep fence: all waves done reading ldsA before re-stage
    }

    if (!WRITE) {
        #pragma unroll
        for (int nf = 0; nf < 4; ++nf) {
            float s = colsum[nf];
            s += __shfl_xor(s, 16);
            s += __shfl_xor(s, 32);
            if (lane < 16) red[wr][wq * 64 + nf * 16 + lane] = s;
        }
        __syncthreads();
        if (tid < 256) {
            float s = (red[0][tid] + red[1][tid]) * 0.0625f;   // exact /16
            __hip_atomic_fetch_add(&sums[(b << 12) + q0 + tid], s,
                                   __ATOMIC_RELAXED, __HIP_MEMORY_SCOPE_AGENT);
        }
    }
}

extern "C" void kernel_launch(void* const* d_in, const int* in_sizes, int n_in,
                              void* d_out, int out_size, void* d_ws, size_t ws_size,
                              hipStream_t stream) {
    const float* Mk = (const float*)d_in[0];
    const float* Qk = (const float*)d_in[1];
    float* out = (float*)d_out;

    _Float16* At   = (_Float16*)d_ws;                               // 4 MB
    _Float16* Bt   = At + (size_t)BATCH * MDIM * CKDIM;             // 4 MB
    float*    sums = (float*)(Bt + (size_t)BATCH * MDIM * CKDIM);   // 64 KB
    float*    cm   = sums + BATCH * QDIM;                           // 64 KB

    convert_kernel<<<256, 256, 0, stream>>>(Mk, Qk, At, Bt, cm, sums);
    gemm_pass<0><<<256, 512, 0, stream>>>(At, Bt, cm, sums, out);
    gemm_pass<1><<<256, 512, 0, stream>>>(At, Bt, cm, sums, out);
}

// Round 9
// 94.678 us; speedup vs baseline: 6.7228x; 6.7228x over previous
//
#include <hip/hip_runtime.h>
#include <cstdint>

#define CKDIM 128
#define MDIM  4096
#define QDIM  4096
#define BATCH 4

typedef __attribute__((ext_vector_type(8))) _Float16 half8;
typedef __attribute__((ext_vector_type(4))) float    f32x4;

#if __has_builtin(__builtin_amdgcn_exp2f)
#define EXP2(x) __builtin_amdgcn_exp2f(x)
#else
#define EXP2(x) exp2f(x)
#endif

#define ALPHA 0.12753139626596757f    // log2(e)/sqrt(128)
#define K2A   0.25506279253193514f    // 2*ALPHA

__device__ inline void gl_lds16(const void* g, void* l) {
    __builtin_amdgcn_global_load_lds(
        (const __attribute__((address_space(1))) unsigned*)g,
        (__attribute__((address_space(3))) unsigned*)l, 16, 0, 0);
}

// ---- 1) fused convert. Outputs CHUNKED layouts (conflict-free + linear-stage):
//   At: per batch, 128 m-tiles of 32 rows: [tile][c=k/8][m%32][8 halves] (8KB tiles)
//   Bt: per batch,  32 q-stripes of 128:   [stripe][c=k/8][q%128][8 halves] (32KB)
//   cm[b][m] = -ALPHA*sum_k Mk^2 (fp32-exact). Qk half zeroes sums[].
__global__ void convert_kernel(const float* __restrict__ Mk, const float* __restrict__ Qk,
                               _Float16* __restrict__ At, _Float16* __restrict__ Bt,
                               float* __restrict__ cm, float* __restrict__ sums) {
    __shared__ _Float16 T[128 * 130];
    __shared__ float    asqp[16][128];
    const int blk = blockIdx.x;                  // 256: mat(2) x b(4) x tile(32)
    const int mat = blk >> 7;
    const int b   = (blk >> 5) & 3;
    const int t   = blk & 31;                    // 128-row tile index
    const float* src = (mat ? Qk : Mk) + (size_t)b * CKDIM * MDIM + t * 128;
    const int tid = threadIdx.x;
    const int kg  = tid >> 4;
    const int ng  = tid & 15;

    float sq[8] = {0.f, 0.f, 0.f, 0.f, 0.f, 0.f, 0.f, 0.f};
    #pragma unroll
    for (int it = 0; it < 8; ++it) {
        int k = it * 16 + kg;
        const float* g = src + (size_t)k * MDIM + ng * 8;
        float4 v0 = *(const float4*)g;
        float4 v1 = *(const float4*)(g + 4);
        _Float16* p = &T[k * 130 + ng * 8];
        p[0] = (_Float16)v0.x; p[1] = (_Float16)v0.y; p[2] = (_Float16)v0.z; p[3] = (_Float16)v0.w;
        p[4] = (_Float16)v1.x; p[5] = (_Float16)v1.y; p[6] = (_Float16)v1.z; p[7] = (_Float16)v1.w;
        if (mat == 0) {
            sq[0] += v0.x * v0.x; sq[1] += v0.y * v0.y;
            sq[2] += v0.z * v0.z; sq[3] += v0.w * v0.w;
            sq[4] += v1.x * v1.x; sq[5] += v1.y * v1.y;
            sq[6] += v1.z * v1.z; sq[7] += v1.w * v1.w;
        }
    }
    if (mat == 0) {
        #pragma unroll
        for (int j = 0; j < 8; ++j) asqp[kg][ng * 8 + j] = sq[j];
    } else {
        if (tid < 128) sums[(blk & 127) * 128 + tid] = 0.f;
    }
    __syncthreads();
    // phase 2: gather k-column per (n, chunk) -> chunked layout, half8 stores
    #pragma unroll
    for (int it = 0; it < 8; ++it) {
        int idx = it * 256 + tid;                // 0..2047 = 16 c x 128 n
        int cc  = idx >> 7;                      // k-chunk 0..15
        int n   = idx & 127;                     // row within this 128-row tile
        half8 o;
        #pragma unroll
        for (int j = 0; j < 8; ++j) o[j] = T[(cc * 8 + j) * 130 + n];
        if (mat == 0) {
            // 32-row tiles: tile = t*4 + n/32
            _Float16* dst = At + (size_t)b * (MDIM * CKDIM)
                          + (size_t)(t * 4 + (n >> 5)) * 4096 + cc * 256 + (n & 31) * 8;
            *(half8*)dst = o;
        } else {
            // 128-q stripes: stripe = t
            _Float16* dst = Bt + (size_t)b * (QDIM * CKDIM)
                          + (size_t)t * 16384 + cc * 1024 + n * 8;
            *(half8*)dst = o;
        }
    }
    if (mat == 0 && tid < 128) {
        float s = 0.f;
        #pragma unroll
        for (int g = 0; g < 16; ++g) s += asqp[g][tid];
        cm[b * MDIM + t * 128 + tid] = -ALPHA * s;
    }
}

// ---- 2/3) GEMM passes. 1024 blocks (4/CU), 256 thr = 4 waves (1m x 4q).
// Per block: batch b, m-seg 512 (16 tiles of 32), q-stripe 128.
// B fragments live in VGPRs (global coalesced loads, no LDS). A staged in
// chunked 8KB tiles (linear gl_lds, conflict-free 256B-contiguous reads),
// double-buffered. WRITE=0: colsum atomics; WRITE=1: write exp/sum.
template <int WRITE>
__global__ __launch_bounds__(256, 4) void gemm_pass(
        const _Float16* __restrict__ At, const _Float16* __restrict__ Bt,
        const float* __restrict__ cmArr, float* __restrict__ sums,
        float* __restrict__ out) {
    __shared__ __align__(16) char ldsA[2][8192];
    const int tid  = threadIdx.x;
    const int lane = tid & 63;
    const int wv   = tid >> 6;      // q-group 0..3 (32 q each)
    const int g4   = lane >> 4;
    const int i    = lane & 15;

    const int wg = blockIdx.x;                      // 0..1023
    const int id = ((wg & 7) << 7) | (wg >> 3);     // XCD-chunked, bijective
    const int b  = id >> 8;
    const int qs = (id >> 3) & 31;
    const int ms = id & 7;
    const int q0 = qs << 7;
    const int m0 = ms << 9;

    const char* Ab = (const char*)At + ((size_t)(b * 128 + ms * 16) << 13);
    const char* Bb = (const char*)Bt + ((size_t)(b * 32 + qs) << 15);
    const int   cmb = (b << 12) + m0;

    // B fragments -> registers (coalesced 256B-per-16-lane-group loads)
    half8 bq[2][4];
    #pragma unroll
    for (int nf = 0; nf < 2; ++nf)
        #pragma unroll
        for (int t = 0; t < 4; ++t)
            bq[nf][t] = *(const half8*)(Bb + (t * 4 + g4) * 2048
                                           + (wv * 32 + nf * 16 + i) * 16);

    float rs0, rs1;
    if (WRITE) {
        rs0 = 1.0f / sums[(b << 12) + q0 + wv * 32 + i];
        rs1 = 1.0f / sums[(b << 12) + q0 + wv * 32 + 16 + i];
    }

    // stage A tile 0 (linear: LDS layout == global layout)
    {
        unsigned o0 = (unsigned)wv * 1024u;
        unsigned o1 = 4096u + (unsigned)wv * 1024u;
        gl_lds16(Ab + o0 + lane * 16, ldsA[0] + o0);
        gl_lds16(Ab + o1 + lane * 16, ldsA[0] + o1);
    }
    f32x4 cm0 = *(const f32x4*)&cmArr[cmb + g4 * 4];
    f32x4 cm1 = *(const f32x4*)&cmArr[cmb + 16 + g4 * 4];
    asm volatile("s_waitcnt vmcnt(0)" ::: "memory");
    __syncthreads();

    float cs0 = 0.f, cs1 = 0.f;

    #pragma unroll 1
    for (int mt = 0; mt < 16; ++mt) {
        const char* lA = ldsA[mt & 1];
        f32x4 cmn0, cmn1;
        if (mt + 1 < 16) {
            const char* Asrc = Ab + ((size_t)(mt + 1) << 13);
            char* dst = ldsA[(mt + 1) & 1];
            unsigned o0 = (unsigned)wv * 1024u;
            unsigned o1 = 4096u + (unsigned)wv * 1024u;
            gl_lds16(Asrc + o0 + lane * 16, dst + o0);
            gl_lds16(Asrc + o1 + lane * 16, dst + o1);
            cmn0 = *(const f32x4*)&cmArr[cmb + (mt + 1) * 32 + g4 * 4];
            cmn1 = *(const f32x4*)&cmArr[cmb + (mt + 1) * 32 + 16 + g4 * 4];
        }
        __builtin_amdgcn_sched_barrier(0);

        f32x4 acc[2][2] = {};
        #pragma unroll
        for (int t = 0; t < 4; ++t) {
            // chunk c = t*4+g4: each 16-lane group reads 256B contiguous
            const char* base = lA + (t * 4 + g4) * 512 + i * 16;
            half8 a0 = *(const half8*)(base);
            half8 a1 = *(const half8*)(base + 256);
            __builtin_amdgcn_s_setprio(1);
            acc[0][0] = __builtin_amdgcn_mfma_f32_16x16x32_f16(a0, bq[0][t], acc[0][0], 0, 0, 0);
            acc[0][1] = __builtin_amdgcn_mfma_f32_16x16x32_f16(a0, bq[1][t], acc[0][1], 0, 0, 0);
            acc[1][0] = __builtin_amdgcn_mfma_f32_16x16x32_f16(a1, bq[0][t], acc[1][0], 0, 0, 0);
            acc[1][1] = __builtin_amdgcn_mfma_f32_16x16x32_f16(a1, bq[1][t], acc[1][1], 0, 0, 0);
            __builtin_amdgcn_s_setprio(0);
        }

        if (WRITE) {
            #pragma unroll
            for (int mf = 0; mf < 2; ++mf) {
                f32x4  cmv  = mf ? cm1 : cm0;
                size_t mrow = (size_t)(m0 + mt * 32 + mf * 16 + g4 * 4);
                size_t base = ((((size_t)b << 12) + mrow) << 12) + (q0 + wv * 32 + i);
                #pragma unroll
                for (int r = 0; r < 4; ++r) {
                    out[base + ((size_t)r << 12)]      = EXP2(fmaf(acc[mf][0][r], K2A, cmv[r])) * rs0;
                    out[base + ((size_t)r << 12) + 16] = EXP2(fmaf(acc[mf][1][r], K2A, cmv[r])) * rs1;
                }
            }
        } else {
            #pragma unroll
            for (int mf = 0; mf < 2; ++mf) {
                f32x4 cmv = mf ? cm1 : cm0;
                #pragma unroll
                for (int r = 0; r < 4; ++r) {
                    cs0 += EXP2(fmaf(acc[mf][0][r], K2A, cmv[r]));
                    cs1 += EXP2(fmaf(acc[mf][1][r], K2A, cmv[r]));
                }
            }
        }

        if (mt + 1 < 16) {
            // oldest 2 outstanding VMEMs = the prefetch; leave cm(+stores) in flight
            if (WRITE) asm volatile("s_waitcnt vmcnt(18)" ::: "memory");
            else       asm volatile("s_waitcnt vmcnt(2)"  ::: "memory");
            __builtin_amdgcn_s_barrier();
            __builtin_amdgcn_sched_barrier(0);
        }
        cm0 = cmn0; cm1 = cmn1;
    }

    if (!WRITE) {
        cs0 += __shfl_xor(cs0, 16); cs0 += __shfl_xor(cs0, 32);
        cs1 += __shfl_xor(cs1, 16); cs1 += __shfl_xor(cs1, 32);
        if (lane < 16) {
            __hip_atomic_fetch_add(&sums[(b << 12) + q0 + wv * 32 + lane], cs0,
                                   __ATOMIC_RELAXED, __HIP_MEMORY_SCOPE_AGENT);
            __hip_atomic_fetch_add(&sums[(b << 12) + q0 + wv * 32 + 16 + lane], cs1,
                                   __ATOMIC_RELAXED, __HIP_MEMORY_SCOPE_AGENT);
        }
    }
}

extern "C" void kernel_launch(void* const* d_in, const int* in_sizes, int n_in,
                              void* d_out, int out_size, void* d_ws, size_t ws_size,
                              hipStream_t stream) {
    const float* Mk = (const float*)d_in[0];
    const float* Qk = (const float*)d_in[1];
    float* out = (float*)d_out;

    _Float16* At   = (_Float16*)d_ws;                               // 4 MB
    _Float16* Bt   = At + (size_t)BATCH * MDIM * CKDIM;             // 4 MB
    float*    sums = (float*)(Bt + (size_t)BATCH * MDIM * CKDIM);   // 64 KB
    float*    cm   = sums + BATCH * QDIM;                           // 64 KB

    convert_kernel<<<256, 256, 0, stream>>>(Mk, Qk, At, Bt, cm, sums);
    gemm_pass<0><<<1024, 256, 0, stream>>>(At, Bt, cm, sums, out);
    gemm_pass<1><<<1024, 256, 0, stream>>>(At, Bt, cm, sums, out);
}